// Round 5
// baseline (661.431 us; speedup 1.0000x reference)
//
#include <hip/hip_runtime.h>
#include <math.h>

#define HH 512
#define WW 512
#define NB 64
#define HW (HH*WW)

struct GaussK { float k[13]; };

__device__ __forceinline__ float idenv(int i) {
    return (float)(2*i - (WW-1)) / (float)(WW-1);
}

#define DEF_OFF ((float)((2.0 + 4.0/511.0)/2.0))
#define BOUND   ((float)(2.0/512.0*8.0))

typedef float vf2 __attribute__((ext_vector_type(2), aligned(4)));

// ---- fused vertical blur (prim ch0) + horizontal blur + row scan -> plane 0 ----
// 256 threads = 4 waves; each wave owns one (b,h) row; lane owns cols 8l..8l+7.
__global__ void __launch_bounds__(256) k_xscan(const float* __restrict__ prim, float* __restrict__ out, GaussK gk) {
    int lane = threadIdx.x & 63;
    int gw   = blockIdx.x*4 + (threadIdx.x >> 6);   // global wave id over B*H
    int b    = gw >> 9;
    int h    = gw & (HH-1);
    const float4* src = (const float4*)(prim + (size_t)b*2*HW);   // channel 0
    float* plane0 = out + (size_t)b*3*HW + (size_t)h*WW;

    int rows[13];
    #pragma unroll
    for (int i = 0; i < 13; ++i) {
        int r = h - 6 + i;
        rows[i] = r < 0 ? -r : (r > HH-1 ? 2*(HH-1) - r : r);
    }

    float a[8];
    #pragma unroll
    for (int t = 0; t < 2; ++t) {
        int g = 2*lane + t;
        float4 acc = {0.f,0.f,0.f,0.f};
        #pragma unroll
        for (int i = 0; i < 13; ++i) {
            float4 v = src[(size_t)rows[i]*128 + g];
            acc.x = fmaf(gk.k[i], v.x, acc.x);
            acc.y = fmaf(gk.k[i], v.y, acc.y);
            acc.z = fmaf(gk.k[i], v.z, acc.z);
            acc.w = fmaf(gk.k[i], v.w, acc.w);
        }
        a[4*t+0] = acc.x; a[4*t+1] = acc.y; a[4*t+2] = acc.z; a[4*t+3] = acc.w;
    }

    float win[21];
    #pragma unroll
    for (int i = 0; i < 7; ++i) {
        float v = __shfl_up(a[i+1], 1, 64);
        win[i] = (lane == 0) ? a[7-i] : v;
    }
    #pragma unroll
    for (int i = 0; i < 8; ++i) win[7+i] = a[i];
    #pragma unroll
    for (int i = 15; i < 21; ++i) {
        float v = __shfl_down(a[i-15], 1, 64);
        win[i] = (lane == 63) ? a[21-i] : v;
    }

    float s[9];
    #pragma unroll
    for (int j = 0; j < 9; ++j) {
        float acc = 0.f;
        #pragma unroll
        for (int i = 0; i < 13; ++i) acc = fmaf(gk.k[i], win[j+i], acc);
        s[j] = acc + idenv(8*lane - 1 + j) + DEF_OFF;
    }
    if (lane == 0) s[0] = 0.f;

    float qs[8], q = 0.f;
    #pragma unroll
    for (int j = 1; j < 9; ++j) { q += fmaxf(s[j] - s[j-1], 0.f); qs[j-1] = q; }
    float inc = q;
    #pragma unroll
    for (int d = 1; d < 64; d <<= 1) {
        float t = __shfl_up(inc, d, 64);
        if (lane >= d) inc += t;
    }
    float excl = inc - q;

    float4 g0, g1;
    float* gp0 = (float*)&g0;
    float* gp1 = (float*)&g1;
    #pragma unroll
    for (int j = 0; j < 8; ++j) {
        int wcol = lane*8 + j;
        float sx = excl + qs[j];
        float p = sx - DEF_OFF - idenv(wcol);
        p = fminf(fmaxf(p, -BOUND), BOUND);
        float g = p + idenv(wcol);
        g = fminf(fmaxf(g, -1.f), 1.f);
        if (j < 4) gp0[j] = g; else gp1[j-4] = g;
    }
    *(float4*)(plane0 + lane*8)     = g0;
    *(float4*)(plane0 + lane*8 + 4) = g1;
}

// ---- fused hblur + vertical blur + column scan (y channel): prim ch1 -> plane 2 ----
// block = 1024 threads = 16 waves; wave ws owns rows [ws*32, ws*32+32);
// horizontal 13-tap conv computed on the fly (coalesced L1-hot loads).
__global__ void __launch_bounds__(1024, 8) k_yscan(const float* __restrict__ prim, float* __restrict__ out, GaussK gk) {
    __shared__ float segsum[16][64];
    int b    = blockIdx.x >> 3;
    int wt   = blockIdx.x & 7;
    int lane = threadIdx.x & 63;
    int ws   = threadIdx.x >> 6;         // 0..15
    int w    = wt*64 + lane;
    const float* src = prim + ((size_t)b*2 + 1)*HW;   // channel 1
    float*       p2  = out + ((size_t)b*3 + 2)*HW + w;
    int r0 = ws*32;

    int xs[13];
    #pragma unroll
    for (int i = 0; i < 13; ++i) {
        int x = w - 6 + i;
        xs[i] = x < 0 ? -x : (x > WW-1 ? 2*(WW-1) - x : x);
    }

    // hblur of (reflected) row r at this thread's column
    #define HROW(r_) ({ int r = (r_); r = r < 0 ? -r : (r > HH-1 ? 2*(HH-1) - r : r); \
                        const float* rp = src + (size_t)r*WW; float hacc = 0.f; \
                        _Pragma("unroll") for (int i_ = 0; i_ < 13; ++i_) hacc = fmaf(gk.k[i_], rp[xs[i_]], hacc); \
                        hacc; })

    // ---------- pass 1: per-segment partial sum ----------
    float qsum = 0.f;
    {
        float win[13], sprev;
        int h;
        if (ws == 0) {
            #pragma unroll
            for (int i = 0; i < 13; ++i) win[i] = HROW(-6 + i);
            sprev = 0.f; h = 0;
        } else {
            #pragma unroll
            for (int i = 0; i < 13; ++i) win[i] = HROW(r0 - 7 + i);
            float acc = 0.f;
            #pragma unroll
            for (int i = 0; i < 13; ++i) acc = fmaf(gk.k[i], win[i], acc);
            sprev = acc + idenv(r0 - 1) + DEF_OFF;
            #pragma unroll
            for (int i = 0; i < 12; ++i) win[i] = win[i+1];
            win[12] = HROW(r0 + 6);
            h = r0;
        }
        for (int n = 0; n < 32; ++n) {
            float acc = 0.f;
            #pragma unroll
            for (int i = 0; i < 13; ++i) acc = fmaf(gk.k[i], win[i], acc);
            float s = acc + idenv(h) + DEF_OFF;
            qsum += fmaxf(s - sprev, 0.f);
            sprev = s;
            ++h;
            if (n < 31) {
                #pragma unroll
                for (int i = 0; i < 12; ++i) win[i] = win[i+1];
                win[12] = HROW(h + 6);
            }
        }
    }
    segsum[ws][lane] = qsum;
    __syncthreads();
    float run = 0.f;
    for (int k = 0; k < ws; ++k) run += segsum[k][lane];

    // ---------- pass 2: recompute + write ----------
    {
        float win[13], sprev;
        int h;
        if (ws == 0) {
            #pragma unroll
            for (int i = 0; i < 13; ++i) win[i] = HROW(-6 + i);
            sprev = 0.f; h = 0;
        } else {
            #pragma unroll
            for (int i = 0; i < 13; ++i) win[i] = HROW(r0 - 7 + i);
            float acc = 0.f;
            #pragma unroll
            for (int i = 0; i < 13; ++i) acc = fmaf(gk.k[i], win[i], acc);
            sprev = acc + idenv(r0 - 1) + DEF_OFF;
            #pragma unroll
            for (int i = 0; i < 12; ++i) win[i] = win[i+1];
            win[12] = HROW(r0 + 6);
            h = r0;
        }
        for (int n = 0; n < 32; ++n) {
            float acc = 0.f;
            #pragma unroll
            for (int i = 0; i < 13; ++i) acc = fmaf(gk.k[i], win[i], acc);
            float s = acc + idenv(h) + DEF_OFF;
            run += fmaxf(s - sprev, 0.f);
            sprev = s;
            float p = run - DEF_OFF - idenv(h);
            p = fminf(fmaxf(p, -BOUND), BOUND);
            float g = p + idenv(h);
            g = fminf(fmaxf(g, -1.f), 1.f);
            p2[(size_t)h*WW] = g;
            ++h;
            if (n < 31) {
                #pragma unroll
                for (int i = 0; i < 12; ++i) win[i] = win[i+1];
                win[12] = HROW(h + 6);
            }
        }
    }
    #undef HROW
}

// ---- bilinear grid sample: 1 px/lane, 2 independent pixels (b, b+32), float2 gathers ----
__global__ void __launch_bounds__(256) k_sample(const float* __restrict__ image, float* __restrict__ out) {
    int idx = blockIdx.x*256 + threadIdx.x;   // over 32*H*W
    int w  = idx & (WW-1);
    int h  = (idx >> 9) & (HH-1);
    int b0 = idx >> 18;                        // 0..31
    int off = h*WW + w;

    #pragma unroll
    for (int u = 0; u < 2; ++u) {
        int b = b0 + 32*u;
        float* ob = out + (size_t)b*3*HW;
        const float* ib = image + (size_t)b*3*HW;
        float gx = __builtin_nontemporal_load(ob + off);
        float gy = __builtin_nontemporal_load(ob + 2*HW + off);
        float fx = (gx + 1.f) * 0.5f * (float)(WW-1);
        float fy = (gy + 1.f) * 0.5f * (float)(HH-1);
        float x0f = floorf(fx), y0f = floorf(fy);
        float wx = fx - x0f, wy = fy - y0f;
        int x0 = (int)x0f, y0 = (int)y0f;
        int y1 = y0 + 1; if (y1 > HH-1) y1 = HH-1;
        bool sh = x0 > WW-2;                    // x0==511 => wx==0 exactly
        int xb = sh ? WW-2 : x0;
        size_t r0 = (size_t)y0*WW + xb;
        size_t r1 = (size_t)y1*WW + xb;
        float w11 = wx*wy;
        float w01 = wx - w11;
        float w10 = wy - w11;
        float w00 = 1.f - wx - wy + w11;
        #pragma unroll
        for (int c = 0; c < 3; ++c) {
            const float* ip = ib + (size_t)c*HW;
            vf2 t  = *(const vf2*)(ip + r0);
            vf2 bo = *(const vf2*)(ip + r1);
            float a00 = sh ? t.y  : t.x;
            float a10 = sh ? bo.y : bo.x;
            float r = a00*w00 + t.y*w01 + a10*w10 + bo.y*w11;
            __builtin_nontemporal_store(r, ob + (size_t)c*HW + off);
        }
    }
}

extern "C" void kernel_launch(void* const* d_in, const int* in_sizes, int n_in,
                              void* d_out, int out_size, void* d_ws, size_t ws_size,
                              hipStream_t stream) {
    const float* image = (const float*)d_in[0];
    const float* prim  = (const float*)d_in[1];
    float* out = (float*)d_out;

    GaussK gk;
    {
        double sigma = 13.0*0.15 + 0.35;   // 2.3
        double pdf[13], sum = 0.0;
        for (int i = 0; i < 13; ++i) {
            double t = (double)(i - 6);
            pdf[i] = exp(-0.5*(t/sigma)*(t/sigma));
            sum += pdf[i];
        }
        for (int i = 0; i < 13; ++i) gk.k[i] = (float)(pdf[i]/sum);
    }

    k_xscan <<<NB*HH/4,        256, 0, stream>>>(prim, out, gk);
    k_yscan <<<NB*8,          1024, 0, stream>>>(prim, out, gk);
    k_sample<<<NB*HH*WW/2/256, 256, 0, stream>>>(image, out);
}

// Round 6
// 289.310 us; speedup vs baseline: 2.2862x; 2.2862x over previous
//
#include <hip/hip_runtime.h>
#include <math.h>

#define HH 512
#define WW 512
#define NB 64
#define HW (HH*WW)

struct GaussK { float k[13]; };

__device__ __forceinline__ float idenv(int i) {
    return (float)(2*i - (WW-1)) / (float)(WW-1);
}

#define DEF_OFF ((float)((2.0 + 4.0/511.0)/2.0))
#define BOUND   ((float)(2.0/512.0*8.0))

typedef float vf2 __attribute__((ext_vector_type(2), aligned(4)));

// ---------------- horizontal blur of prim ch1 -> out plane 1 (4 px/thread) ----------------
__global__ void k_hblur(const float* __restrict__ prim, float* __restrict__ out, GaussK gk) {
    int idx = blockIdx.x*256 + threadIdx.x;          // over B*H*W/4
    int w4 = idx & 127;
    int h  = (idx >> 7) & (HH-1);
    int b  = idx >> 16;
    const float* src = prim + ((size_t)b*2 + 1)*HW + (size_t)h*WW;
    float t[16];                                     // cols 4*w4-6 .. 4*w4+9
    #pragma unroll
    for (int j = 0; j < 16; ++j) {
        int x = w4*4 - 6 + j;
        x = x < 0 ? -x : (x > WW-1 ? 2*(WW-1) - x : x);
        t[j] = src[x];
    }
    float4 o;
    float* op = (float*)&o;
    #pragma unroll
    for (int j = 0; j < 4; ++j) {
        float acc = 0.f;
        #pragma unroll
        for (int i = 0; i < 13; ++i) acc = fmaf(gk.k[i], t[j+i], acc);
        op[j] = acc;
    }
    ((float4*)(out + ((size_t)b*3 + 1)*HW))[(size_t)h*128 + w4] = o;
}

// ---- fused vertical blur (prim ch0) + horizontal blur + row scan -> plane 0 ----
// 256 threads = 4 waves; each wave owns one (b,h) row; lane owns cols 8l..8l+7.
// XCD-chunked swizzle: adjacent h rows (which share 12/16 input rows) -> same XCD L2.
__global__ void __launch_bounds__(256) k_xscan(const float* __restrict__ prim, float* __restrict__ out, GaussK gk) {
    int lane = threadIdx.x & 63;
    int bid  = (int)blockIdx.x;                      // 8192 blocks
    int work = (bid & 7)*1024 + (bid >> 3);          // bijective, 8192%8==0
    int gw   = work*4 + (threadIdx.x >> 6);          // global wave id over B*H
    int b    = gw >> 9;
    int h    = gw & (HH-1);
    const float4* src = (const float4*)(prim + (size_t)b*2*HW);   // channel 0
    float* plane0 = out + (size_t)b*3*HW + (size_t)h*WW;

    int rows[13];
    #pragma unroll
    for (int i = 0; i < 13; ++i) {
        int r = h - 6 + i;
        rows[i] = r < 0 ? -r : (r > HH-1 ? 2*(HH-1) - r : r);
    }

    float a[8];
    #pragma unroll
    for (int t = 0; t < 2; ++t) {
        int g = 2*lane + t;
        float4 acc = {0.f,0.f,0.f,0.f};
        #pragma unroll
        for (int i = 0; i < 13; ++i) {
            float4 v = src[(size_t)rows[i]*128 + g];
            acc.x = fmaf(gk.k[i], v.x, acc.x);
            acc.y = fmaf(gk.k[i], v.y, acc.y);
            acc.z = fmaf(gk.k[i], v.z, acc.z);
            acc.w = fmaf(gk.k[i], v.w, acc.w);
        }
        a[4*t+0] = acc.x; a[4*t+1] = acc.y; a[4*t+2] = acc.z; a[4*t+3] = acc.w;
    }

    float win[21];
    #pragma unroll
    for (int i = 0; i < 7; ++i) {
        float v = __shfl_up(a[i+1], 1, 64);
        win[i] = (lane == 0) ? a[7-i] : v;
    }
    #pragma unroll
    for (int i = 0; i < 8; ++i) win[7+i] = a[i];
    #pragma unroll
    for (int i = 15; i < 21; ++i) {
        float v = __shfl_down(a[i-15], 1, 64);
        win[i] = (lane == 63) ? a[21-i] : v;
    }

    float s[9];
    #pragma unroll
    for (int j = 0; j < 9; ++j) {
        float acc = 0.f;
        #pragma unroll
        for (int i = 0; i < 13; ++i) acc = fmaf(gk.k[i], win[j+i], acc);
        s[j] = acc + idenv(8*lane - 1 + j) + DEF_OFF;
    }
    if (lane == 0) s[0] = 0.f;

    float qs[8], q = 0.f;
    #pragma unroll
    for (int j = 1; j < 9; ++j) { q += fmaxf(s[j] - s[j-1], 0.f); qs[j-1] = q; }
    float inc = q;
    #pragma unroll
    for (int d = 1; d < 64; d <<= 1) {
        float t = __shfl_up(inc, d, 64);
        if (lane >= d) inc += t;
    }
    float excl = inc - q;

    float4 g0, g1;
    float* gp0 = (float*)&g0;
    float* gp1 = (float*)&g1;
    #pragma unroll
    for (int j = 0; j < 8; ++j) {
        int wcol = lane*8 + j;
        float sx = excl + qs[j];
        float p = sx - DEF_OFF - idenv(wcol);
        p = fminf(fmaxf(p, -BOUND), BOUND);
        float g = p + idenv(wcol);
        g = fminf(fmaxf(g, -1.f), 1.f);
        if (j < 4) gp0[j] = g; else gp1[j-4] = g;
    }
    *(float4*)(plane0 + lane*8)     = g0;
    *(float4*)(plane0 + lane*8 + 4) = g1;
}

// ---- fused vertical blur + column scan (y channel): read plane 1, write plane 2 ----
// block = 1024 threads = 16 waves; wave ws owns rows [ws*32, ws*32+32)  (R4-proven)
__global__ void __launch_bounds__(1024) k_yscan(float* __restrict__ out, GaussK gk) {
    __shared__ float segsum[16][64];
    int b    = blockIdx.x >> 3;
    int wt   = blockIdx.x & 7;
    int lane = threadIdx.x & 63;
    int ws   = threadIdx.x >> 6;         // 0..15
    int w    = wt*64 + lane;
    const float* p1 = out + ((size_t)b*3 + 1)*HW + w;
    float*       p2 = out + ((size_t)b*3 + 2)*HW + w;
    int r0 = ws*32;

    #define LDROW(r_) ({ int r = (r_); r = r < 0 ? -r : (r > HH-1 ? 2*(HH-1) - r : r); \
                         p1[(size_t)r*WW]; })

    float qsum = 0.f;
    {
        float win[13], sprev;
        int h;
        if (ws == 0) {
            #pragma unroll
            for (int i = 0; i < 13; ++i) win[i] = LDROW(-6 + i);
            sprev = 0.f; h = 0;
        } else {
            #pragma unroll
            for (int i = 0; i < 13; ++i) win[i] = LDROW(r0 - 7 + i);
            float acc = 0.f;
            #pragma unroll
            for (int i = 0; i < 13; ++i) acc = fmaf(gk.k[i], win[i], acc);
            sprev = acc + idenv(r0 - 1) + DEF_OFF;
            #pragma unroll
            for (int i = 0; i < 12; ++i) win[i] = win[i+1];
            win[12] = LDROW(r0 + 6);
            h = r0;
        }
        for (int n = 0; n < 32; ++n) {
            float acc = 0.f;
            #pragma unroll
            for (int i = 0; i < 13; ++i) acc = fmaf(gk.k[i], win[i], acc);
            float s = acc + idenv(h) + DEF_OFF;
            qsum += fmaxf(s - sprev, 0.f);
            sprev = s;
            ++h;
            if (n < 31) {
                #pragma unroll
                for (int i = 0; i < 12; ++i) win[i] = win[i+1];
                win[12] = LDROW(h + 6);
            }
        }
    }
    segsum[ws][lane] = qsum;
    __syncthreads();
    float run = 0.f;
    for (int k = 0; k < ws; ++k) run += segsum[k][lane];

    {
        float win[13], sprev;
        int h;
        if (ws == 0) {
            #pragma unroll
            for (int i = 0; i < 13; ++i) win[i] = LDROW(-6 + i);
            sprev = 0.f; h = 0;
        } else {
            #pragma unroll
            for (int i = 0; i < 13; ++i) win[i] = LDROW(r0 - 7 + i);
            float acc = 0.f;
            #pragma unroll
            for (int i = 0; i < 13; ++i) acc = fmaf(gk.k[i], win[i], acc);
            sprev = acc + idenv(r0 - 1) + DEF_OFF;
            #pragma unroll
            for (int i = 0; i < 12; ++i) win[i] = win[i+1];
            win[12] = LDROW(r0 + 6);
            h = r0;
        }
        for (int n = 0; n < 32; ++n) {
            float acc = 0.f;
            #pragma unroll
            for (int i = 0; i < 13; ++i) acc = fmaf(gk.k[i], win[i], acc);
            float s = acc + idenv(h) + DEF_OFF;
            run += fmaxf(s - sprev, 0.f);
            sprev = s;
            float p = run - DEF_OFF - idenv(h);
            p = fminf(fmaxf(p, -BOUND), BOUND);
            float g = p + idenv(h);
            g = fminf(fmaxf(g, -1.f), 1.f);
            p2[(size_t)h*WW] = g;
            ++h;
            if (n < 31) {
                #pragma unroll
                for (int i = 0; i < 12; ++i) win[i] = win[i+1];
                win[12] = LDROW(h + 6);
            }
        }
    }
    #undef LDROW
}

// ---- bilinear grid sample: 1 px/lane, 2 batches/thread, float2 gathers, XCD swizzle ----
__global__ void __launch_bounds__(256) k_sample(const float* __restrict__ image, float* __restrict__ out) {
    int bid  = (int)blockIdx.x;                 // 32768 blocks
    int work = (bid & 7)*4096 + (bid >> 3);     // bijective, 32768%8==0
    int idx  = work*256 + threadIdx.x;          // over 32*H*W
    int w  = idx & (WW-1);
    int h  = (idx >> 9) & (HH-1);
    int b0 = idx >> 18;                         // 0..31
    int off = h*WW + w;

    #pragma unroll
    for (int u = 0; u < 2; ++u) {
        int b = b0 + 32*u;
        float* ob = out + (size_t)b*3*HW;
        const float* ib = image + (size_t)b*3*HW;
        float gx = __builtin_nontemporal_load(ob + off);
        float gy = __builtin_nontemporal_load(ob + 2*HW + off);
        float fx = (gx + 1.f) * 0.5f * (float)(WW-1);
        float fy = (gy + 1.f) * 0.5f * (float)(HH-1);
        float x0f = floorf(fx), y0f = floorf(fy);
        float wx = fx - x0f, wy = fy - y0f;
        int x0 = (int)x0f, y0 = (int)y0f;
        int y1 = y0 + 1; if (y1 > HH-1) y1 = HH-1;
        bool sh = x0 > WW-2;                    // x0==511 => wx==0 exactly
        int xb = sh ? WW-2 : x0;
        size_t r0 = (size_t)y0*WW + xb;
        size_t r1 = (size_t)y1*WW + xb;
        float w11 = wx*wy;
        float w01 = wx - w11;
        float w10 = wy - w11;
        float w00 = 1.f - wx - wy + w11;
        #pragma unroll
        for (int c = 0; c < 3; ++c) {
            const float* ip = ib + (size_t)c*HW;
            vf2 t  = *(const vf2*)(ip + r0);
            vf2 bo = *(const vf2*)(ip + r1);
            float a00 = sh ? t.y  : t.x;
            float a10 = sh ? bo.y : bo.x;
            float r = a00*w00 + t.y*w01 + a10*w10 + bo.y*w11;
            __builtin_nontemporal_store(r, ob + (size_t)c*HW + off);
        }
    }
}

extern "C" void kernel_launch(void* const* d_in, const int* in_sizes, int n_in,
                              void* d_out, int out_size, void* d_ws, size_t ws_size,
                              hipStream_t stream) {
    const float* image = (const float*)d_in[0];
    const float* prim  = (const float*)d_in[1];
    float* out = (float*)d_out;

    GaussK gk;
    {
        double sigma = 13.0*0.15 + 0.35;   // 2.3
        double pdf[13], sum = 0.0;
        for (int i = 0; i < 13; ++i) {
            double t = (double)(i - 6);
            pdf[i] = exp(-0.5*(t/sigma)*(t/sigma));
            sum += pdf[i];
        }
        for (int i = 0; i < 13; ++i) gk.k[i] = (float)(pdf[i]/sum);
    }

    int nQuad = NB*HH*WW/4;               // 4,194,304
    k_hblur <<<nQuad/256,      256, 0, stream>>>(prim, out, gk);
    k_xscan <<<NB*HH/4,        256, 0, stream>>>(prim, out, gk);
    k_yscan <<<NB*8,          1024, 0, stream>>>(out, gk);
    k_sample<<<NB*HH*WW/2/256, 256, 0, stream>>>(image, out);
}

// Round 7
// 278.914 us; speedup vs baseline: 2.3715x; 1.0373x over previous
//
#include <hip/hip_runtime.h>
#include <math.h>

#define HH 512
#define WW 512
#define NB 64
#define HW (HH*WW)

struct GaussK { float k[13]; };

__device__ __forceinline__ float idenv(int i) {
    return (float)(2*i - (WW-1)) / (float)(WW-1);
}

#define DEF_OFF ((float)((2.0 + 4.0/511.0)/2.0))
#define BOUND   ((float)(2.0/512.0*8.0))

typedef float vf2 __attribute__((ext_vector_type(2), aligned(4)));

// ---- merged prep pass 1: role-split hblur (2/3 of blocks) + xscan (1/3) ----
// Interleaved roles (bid%3) so BW-bound hblur and latency-bound xscan co-reside.
__global__ void __launch_bounds__(256) k_prep(const float* __restrict__ prim, float* __restrict__ out, GaussK gk) {
    int bid = (int)blockIdx.x;              // 24576 blocks
    int r3  = bid % 3;
    if (r3 != 2) {
        // ---------- hblur role: prim ch1 -> plane 1, 4 px/thread ----------
        int hb  = (bid/3)*2 + r3;           // 0..16383
        int idx = hb*256 + (int)threadIdx.x;
        int w4 = idx & 127;
        int h  = (idx >> 7) & (HH-1);
        int b  = idx >> 16;
        const float* src = prim + ((size_t)b*2 + 1)*HW + (size_t)h*WW;
        float t[16];
        #pragma unroll
        for (int j = 0; j < 16; ++j) {
            int x = w4*4 - 6 + j;
            x = x < 0 ? -x : (x > WW-1 ? 2*(WW-1) - x : x);
            t[j] = src[x];
        }
        float4 o;
        float* op = (float*)&o;
        #pragma unroll
        for (int j = 0; j < 4; ++j) {
            float acc = 0.f;
            #pragma unroll
            for (int i = 0; i < 13; ++i) acc = fmaf(gk.k[i], t[j+i], acc);
            op[j] = acc;
        }
        ((float4*)(out + ((size_t)b*3 + 1)*HW))[(size_t)h*128 + w4] = o;
        return;
    }

    // ---------- xscan role: fused vblur(ch0)+hblur+row-scan -> plane 0 ----------
    int m    = bid / 3;                      // 0..8191
    int work = (m & 7)*1024 + (m >> 3);      // same-XCD h-chunking (bijective)
    int lane = threadIdx.x & 63;
    int gw   = work*4 + ((int)threadIdx.x >> 6);
    int b    = gw >> 9;
    int h    = gw & (HH-1);
    const float4* src = (const float4*)(prim + (size_t)b*2*HW);   // channel 0
    float* plane0 = out + (size_t)b*3*HW + (size_t)h*WW;

    int rows[13];
    #pragma unroll
    for (int i = 0; i < 13; ++i) {
        int r = h - 6 + i;
        rows[i] = r < 0 ? -r : (r > HH-1 ? 2*(HH-1) - r : r);
    }

    float a[8];
    #pragma unroll
    for (int t = 0; t < 2; ++t) {
        int g = 2*lane + t;
        float4 acc = {0.f,0.f,0.f,0.f};
        #pragma unroll
        for (int i = 0; i < 13; ++i) {
            float4 v = src[(size_t)rows[i]*128 + g];
            acc.x = fmaf(gk.k[i], v.x, acc.x);
            acc.y = fmaf(gk.k[i], v.y, acc.y);
            acc.z = fmaf(gk.k[i], v.z, acc.z);
            acc.w = fmaf(gk.k[i], v.w, acc.w);
        }
        a[4*t+0] = acc.x; a[4*t+1] = acc.y; a[4*t+2] = acc.z; a[4*t+3] = acc.w;
    }

    float win[21];
    #pragma unroll
    for (int i = 0; i < 7; ++i) {
        float v = __shfl_up(a[i+1], 1, 64);
        win[i] = (lane == 0) ? a[7-i] : v;
    }
    #pragma unroll
    for (int i = 0; i < 8; ++i) win[7+i] = a[i];
    #pragma unroll
    for (int i = 15; i < 21; ++i) {
        float v = __shfl_down(a[i-15], 1, 64);
        win[i] = (lane == 63) ? a[21-i] : v;
    }

    float s[9];
    #pragma unroll
    for (int j = 0; j < 9; ++j) {
        float acc = 0.f;
        #pragma unroll
        for (int i = 0; i < 13; ++i) acc = fmaf(gk.k[i], win[j+i], acc);
        s[j] = acc + idenv(8*lane - 1 + j) + DEF_OFF;
    }
    if (lane == 0) s[0] = 0.f;

    float qs[8], q = 0.f;
    #pragma unroll
    for (int j = 1; j < 9; ++j) { q += fmaxf(s[j] - s[j-1], 0.f); qs[j-1] = q; }
    float inc = q;
    #pragma unroll
    for (int d = 1; d < 64; d <<= 1) {
        float t = __shfl_up(inc, d, 64);
        if (lane >= d) inc += t;
    }
    float excl = inc - q;

    float4 g0, g1;
    float* gp0 = (float*)&g0;
    float* gp1 = (float*)&g1;
    #pragma unroll
    for (int j = 0; j < 8; ++j) {
        int wcol = lane*8 + j;
        float sx = excl + qs[j];
        float p = sx - DEF_OFF - idenv(wcol);
        p = fminf(fmaxf(p, -BOUND), BOUND);
        float g = p + idenv(wcol);
        g = fminf(fmaxf(g, -1.f), 1.f);
        if (j < 4) gp0[j] = g; else gp1[j-4] = g;
    }
    *(float4*)(plane0 + lane*8)     = g0;
    *(float4*)(plane0 + lane*8 + 4) = g1;
}

// ---- single-pass vertical blur + column scan: plane 1 -> plane 2 ----
// 1024 thr = 16 waves; wave ws owns rows [ws*32, ws*32+32). All 45 window rows
// loaded up-front into registers (max MLP), convs fully unrolled (no shifts),
// local prefix kept in regs -> one LDS cross-wave scan -> 32 coalesced stores.
__global__ void __launch_bounds__(1024) k_yscan(float* __restrict__ out, GaussK gk) {
    __shared__ float segsum[16][64];
    int b    = blockIdx.x >> 3;
    int wt   = blockIdx.x & 7;
    int lane = threadIdx.x & 63;
    int ws   = threadIdx.x >> 6;         // 0..15
    int w    = wt*64 + lane;
    const float* p1 = out + ((size_t)b*3 + 1)*HW + w;
    float*       p2 = out + ((size_t)b*3 + 2)*HW + w;
    int r0 = ws*32;

    float v[45];                          // rows r0-7 .. r0+37, reflected
    #pragma unroll
    for (int j = 0; j < 45; ++j) {
        int r = r0 - 7 + j;
        r = r < 0 ? -r : (r > HH-1 ? 2*(HH-1) - r : r);
        v[j] = p1[(size_t)r*WW];
    }

    float sprev;
    if (ws == 0) {
        sprev = 0.f;
    } else {
        float acc = 0.f;
        #pragma unroll
        for (int i = 0; i < 13; ++i) acc = fmaf(gk.k[i], v[i], acc);
        sprev = acc + idenv(r0 - 1) + DEF_OFF;
    }

    float q[32];
    float run = 0.f;
    #pragma unroll
    for (int n = 0; n < 32; ++n) {
        float acc = 0.f;
        #pragma unroll
        for (int i = 0; i < 13; ++i) acc = fmaf(gk.k[i], v[n+1+i], acc);
        float s = acc + idenv(r0 + n) + DEF_OFF;
        run += fmaxf(s - sprev, 0.f);
        q[n] = run;
        sprev = s;
    }
    segsum[ws][lane] = run;
    __syncthreads();
    float off = 0.f;
    for (int k = 0; k < ws; ++k) off += segsum[k][lane];

    #pragma unroll
    for (int n = 0; n < 32; ++n) {
        int h = r0 + n;
        float p = off + q[n] - DEF_OFF - idenv(h);
        p = fminf(fmaxf(p, -BOUND), BOUND);
        float g = p + idenv(h);
        g = fminf(fmaxf(g, -1.f), 1.f);
        p2[(size_t)h*WW] = g;
    }
}

// ---- bilinear grid sample: 1 px/lane, 2 batches/thread, float2 gathers, XCD swizzle ----
__global__ void __launch_bounds__(256) k_sample(const float* __restrict__ image, float* __restrict__ out) {
    int bid  = (int)blockIdx.x;                 // 32768 blocks
    int work = (bid & 7)*4096 + (bid >> 3);     // bijective, 32768%8==0
    int idx  = work*256 + threadIdx.x;          // over 32*H*W
    int w  = idx & (WW-1);
    int h  = (idx >> 9) & (HH-1);
    int b0 = idx >> 18;                         // 0..31
    int off = h*WW + w;

    #pragma unroll
    for (int u = 0; u < 2; ++u) {
        int b = b0 + 32*u;
        float* ob = out + (size_t)b*3*HW;
        const float* ib = image + (size_t)b*3*HW;
        float gx = __builtin_nontemporal_load(ob + off);
        float gy = __builtin_nontemporal_load(ob + 2*HW + off);
        float fx = (gx + 1.f) * 0.5f * (float)(WW-1);
        float fy = (gy + 1.f) * 0.5f * (float)(HH-1);
        float x0f = floorf(fx), y0f = floorf(fy);
        float wx = fx - x0f, wy = fy - y0f;
        int x0 = (int)x0f, y0 = (int)y0f;
        int y1 = y0 + 1; if (y1 > HH-1) y1 = HH-1;
        bool sh = x0 > WW-2;                    // x0==511 => wx==0 exactly
        int xb = sh ? WW-2 : x0;
        size_t r0 = (size_t)y0*WW + xb;
        size_t r1 = (size_t)y1*WW + xb;
        float w11 = wx*wy;
        float w01 = wx - w11;
        float w10 = wy - w11;
        float w00 = 1.f - wx - wy + w11;
        #pragma unroll
        for (int c = 0; c < 3; ++c) {
            const float* ip = ib + (size_t)c*HW;
            vf2 t  = *(const vf2*)(ip + r0);
            vf2 bo = *(const vf2*)(ip + r1);
            float a00 = sh ? t.y  : t.x;
            float a10 = sh ? bo.y : bo.x;
            float r = a00*w00 + t.y*w01 + a10*w10 + bo.y*w11;
            __builtin_nontemporal_store(r, ob + (size_t)c*HW + off);
        }
    }
}

extern "C" void kernel_launch(void* const* d_in, const int* in_sizes, int n_in,
                              void* d_out, int out_size, void* d_ws, size_t ws_size,
                              hipStream_t stream) {
    const float* image = (const float*)d_in[0];
    const float* prim  = (const float*)d_in[1];
    float* out = (float*)d_out;

    GaussK gk;
    {
        double sigma = 13.0*0.15 + 0.35;   // 2.3
        double pdf[13], sum = 0.0;
        for (int i = 0; i < 13; ++i) {
            double t = (double)(i - 6);
            pdf[i] = exp(-0.5*(t/sigma)*(t/sigma));
            sum += pdf[i];
        }
        for (int i = 0; i < 13; ++i) gk.k[i] = (float)(pdf[i]/sum);
    }

    k_prep  <<<24576,          256, 0, stream>>>(prim, out, gk);
    k_yscan <<<NB*8,          1024, 0, stream>>>(out, gk);
    k_sample<<<NB*HH*WW/2/256, 256, 0, stream>>>(image, out);
}

// Round 8
// 271.136 us; speedup vs baseline: 2.4395x; 1.0287x over previous
//
#include <hip/hip_runtime.h>
#include <math.h>

#define HH 512
#define WW 512
#define NB 64
#define HW (HH*WW)

struct GaussK { float k[13]; };

__device__ __forceinline__ float idenv(int i) {
    return (float)(2*i - (WW-1)) / (float)(WW-1);
}

#define DEF_OFF ((float)((2.0 + 4.0/511.0)/2.0))
#define BOUND   ((float)(2.0/512.0*8.0))

typedef float vf2 __attribute__((ext_vector_type(2), aligned(4)));

// ---------------- horizontal blur of prim ch1 -> out plane 1 (4 px/thread) ----------------
// interior lanes: 5 aligned float4 loads (cols 4w4-8 .. 4w4+11); edge lanes scalar reflect
__global__ void __launch_bounds__(256) k_hblur(const float* __restrict__ prim, float* __restrict__ out, GaussK gk) {
    int idx = blockIdx.x*256 + threadIdx.x;          // over B*H*W/4
    int w4 = idx & 127;
    int h  = (idx >> 7) & (HH-1);
    int b  = idx >> 16;
    const float* src = prim + ((size_t)b*2 + 1)*HW + (size_t)h*WW;
    float t[16];                                     // cols 4*w4-6 .. 4*w4+9
    if (w4 >= 2 && w4 <= 125) {
        const float4* s4 = (const float4*)(src) + (w4 - 2);
        float flat[20];
        #pragma unroll
        for (int j = 0; j < 5; ++j) {
            float4 v = s4[j];
            flat[4*j+0] = v.x; flat[4*j+1] = v.y; flat[4*j+2] = v.z; flat[4*j+3] = v.w;
        }
        #pragma unroll
        for (int j = 0; j < 16; ++j) t[j] = flat[j+2];
    } else {
        #pragma unroll
        for (int j = 0; j < 16; ++j) {
            int x = w4*4 - 6 + j;
            x = x < 0 ? -x : (x > WW-1 ? 2*(WW-1) - x : x);
            t[j] = src[x];
        }
    }
    float4 o;
    float* op = (float*)&o;
    #pragma unroll
    for (int j = 0; j < 4; ++j) {
        float acc = 0.f;
        #pragma unroll
        for (int i = 0; i < 13; ++i) acc = fmaf(gk.k[i], t[j+i], acc);
        op[j] = acc;
    }
    ((float4*)(out + ((size_t)b*3 + 1)*HW))[(size_t)h*128 + w4] = o;
}

// ---- fused vertical blur (prim ch0) + horizontal blur + row scan -> plane 0 ----
// 256 threads = 4 waves; each wave owns one (b,h) row; lane owns cols 8l..8l+7.
// XCD-chunked swizzle: adjacent h rows (which share 12/16 input rows) -> same XCD L2.
__global__ void __launch_bounds__(256) k_xscan(const float* __restrict__ prim, float* __restrict__ out, GaussK gk) {
    int lane = threadIdx.x & 63;
    int bid  = (int)blockIdx.x;                      // 8192 blocks
    int work = (bid & 7)*1024 + (bid >> 3);          // bijective, 8192%8==0
    int gw   = work*4 + (threadIdx.x >> 6);          // global wave id over B*H
    int b    = gw >> 9;
    int h    = gw & (HH-1);
    const float4* src = (const float4*)(prim + (size_t)b*2*HW);   // channel 0
    float* plane0 = out + (size_t)b*3*HW + (size_t)h*WW;

    int rows[13];
    #pragma unroll
    for (int i = 0; i < 13; ++i) {
        int r = h - 6 + i;
        rows[i] = r < 0 ? -r : (r > HH-1 ? 2*(HH-1) - r : r);
    }

    float a[8];
    #pragma unroll
    for (int t = 0; t < 2; ++t) {
        int g = 2*lane + t;
        float4 acc = {0.f,0.f,0.f,0.f};
        #pragma unroll
        for (int i = 0; i < 13; ++i) {
            float4 v = src[(size_t)rows[i]*128 + g];
            acc.x = fmaf(gk.k[i], v.x, acc.x);
            acc.y = fmaf(gk.k[i], v.y, acc.y);
            acc.z = fmaf(gk.k[i], v.z, acc.z);
            acc.w = fmaf(gk.k[i], v.w, acc.w);
        }
        a[4*t+0] = acc.x; a[4*t+1] = acc.y; a[4*t+2] = acc.z; a[4*t+3] = acc.w;
    }

    float win[21];
    #pragma unroll
    for (int i = 0; i < 7; ++i) {
        float v = __shfl_up(a[i+1], 1, 64);
        win[i] = (lane == 0) ? a[7-i] : v;
    }
    #pragma unroll
    for (int i = 0; i < 8; ++i) win[7+i] = a[i];
    #pragma unroll
    for (int i = 15; i < 21; ++i) {
        float v = __shfl_down(a[i-15], 1, 64);
        win[i] = (lane == 63) ? a[21-i] : v;
    }

    float s[9];
    #pragma unroll
    for (int j = 0; j < 9; ++j) {
        float acc = 0.f;
        #pragma unroll
        for (int i = 0; i < 13; ++i) acc = fmaf(gk.k[i], win[j+i], acc);
        s[j] = acc + idenv(8*lane - 1 + j) + DEF_OFF;
    }
    if (lane == 0) s[0] = 0.f;

    float qs[8], q = 0.f;
    #pragma unroll
    for (int j = 1; j < 9; ++j) { q += fmaxf(s[j] - s[j-1], 0.f); qs[j-1] = q; }
    float inc = q;
    #pragma unroll
    for (int d = 1; d < 64; d <<= 1) {
        float t = __shfl_up(inc, d, 64);
        if (lane >= d) inc += t;
    }
    float excl = inc - q;

    float4 g0, g1;
    float* gp0 = (float*)&g0;
    float* gp1 = (float*)&g1;
    #pragma unroll
    for (int j = 0; j < 8; ++j) {
        int wcol = lane*8 + j;
        float sx = excl + qs[j];
        float p = sx - DEF_OFF - idenv(wcol);
        p = fminf(fmaxf(p, -BOUND), BOUND);
        float g = p + idenv(wcol);
        g = fminf(fmaxf(g, -1.f), 1.f);
        if (j < 4) gp0[j] = g; else gp1[j-4] = g;
    }
    *(float4*)(plane0 + lane*8)     = g0;
    *(float4*)(plane0 + lane*8 + 4) = g1;
}

// ---- single-pass vertical blur + column scan: plane 1 -> plane 2 ----
// 1024 thr = 16 waves; wave ws owns rows [ws*32, ws*32+32). All 45 window rows
// loaded up-front into registers (max MLP), convs fully unrolled.
__global__ void __launch_bounds__(1024) k_yscan(float* __restrict__ out, GaussK gk) {
    __shared__ float segsum[16][64];
    int b    = blockIdx.x >> 3;
    int wt   = blockIdx.x & 7;
    int lane = threadIdx.x & 63;
    int ws   = threadIdx.x >> 6;         // 0..15
    int w    = wt*64 + lane;
    const float* p1 = out + ((size_t)b*3 + 1)*HW + w;
    float*       p2 = out + ((size_t)b*3 + 2)*HW + w;
    int r0 = ws*32;

    float v[45];                          // rows r0-7 .. r0+37, reflected
    #pragma unroll
    for (int j = 0; j < 45; ++j) {
        int r = r0 - 7 + j;
        r = r < 0 ? -r : (r > HH-1 ? 2*(HH-1) - r : r);
        v[j] = p1[(size_t)r*WW];
    }

    float sprev;
    if (ws == 0) {
        sprev = 0.f;
    } else {
        float acc = 0.f;
        #pragma unroll
        for (int i = 0; i < 13; ++i) acc = fmaf(gk.k[i], v[i], acc);
        sprev = acc + idenv(r0 - 1) + DEF_OFF;
    }

    float q[32];
    float run = 0.f;
    #pragma unroll
    for (int n = 0; n < 32; ++n) {
        float acc = 0.f;
        #pragma unroll
        for (int i = 0; i < 13; ++i) acc = fmaf(gk.k[i], v[n+1+i], acc);
        float s = acc + idenv(r0 + n) + DEF_OFF;
        run += fmaxf(s - sprev, 0.f);
        q[n] = run;
        sprev = s;
    }
    segsum[ws][lane] = run;
    __syncthreads();
    float off = 0.f;
    for (int k = 0; k < ws; ++k) off += segsum[k][lane];

    #pragma unroll
    for (int n = 0; n < 32; ++n) {
        int h = r0 + n;
        float p = off + q[n] - DEF_OFF - idenv(h);
        p = fminf(fmaxf(p, -BOUND), BOUND);
        float g = p + idenv(h);
        g = fminf(fmaxf(g, -1.f), 1.f);
        p2[(size_t)h*WW] = g;
    }
}

// ---- bilinear grid sample: 1 px/lane, 2 batches/thread, float2 gathers, XCD swizzle ----
// grid reads are plain loads (L2-hot from writers); stores nontemporal.
__global__ void __launch_bounds__(256) k_sample(const float* __restrict__ image, float* __restrict__ out) {
    int bid  = (int)blockIdx.x;                 // 32768 blocks
    int work = (bid & 7)*4096 + (bid >> 3);     // bijective, 32768%8==0
    int idx  = work*256 + threadIdx.x;          // over 32*H*W
    int w  = idx & (WW-1);
    int h  = (idx >> 9) & (HH-1);
    int b0 = idx >> 18;                         // 0..31
    int off = h*WW + w;

    #pragma unroll
    for (int u = 0; u < 2; ++u) {
        int b = b0 + 32*u;
        float* ob = out + (size_t)b*3*HW;
        const float* ib = image + (size_t)b*3*HW;
        float gx = ob[off];
        float gy = ob[2*HW + off];
        float fx = (gx + 1.f) * 0.5f * (float)(WW-1);
        float fy = (gy + 1.f) * 0.5f * (float)(HH-1);
        float x0f = floorf(fx), y0f = floorf(fy);
        float wx = fx - x0f, wy = fy - y0f;
        int x0 = (int)x0f, y0 = (int)y0f;
        int y1 = y0 + 1; if (y1 > HH-1) y1 = HH-1;
        bool sh = x0 > WW-2;                    // x0==511 => wx==0 exactly
        int xb = sh ? WW-2 : x0;
        size_t r0 = (size_t)y0*WW + xb;
        size_t r1 = (size_t)y1*WW + xb;
        float w11 = wx*wy;
        float w01 = wx - w11;
        float w10 = wy - w11;
        float w00 = 1.f - wx - wy + w11;
        #pragma unroll
        for (int c = 0; c < 3; ++c) {
            const float* ip = ib + (size_t)c*HW;
            vf2 t  = *(const vf2*)(ip + r0);
            vf2 bo = *(const vf2*)(ip + r1);
            float a00 = sh ? t.y  : t.x;
            float a10 = sh ? bo.y : bo.x;
            float r = a00*w00 + t.y*w01 + a10*w10 + bo.y*w11;
            __builtin_nontemporal_store(r, ob + (size_t)c*HW + off);
        }
    }
}

extern "C" void kernel_launch(void* const* d_in, const int* in_sizes, int n_in,
                              void* d_out, int out_size, void* d_ws, size_t ws_size,
                              hipStream_t stream) {
    const float* image = (const float*)d_in[0];
    const float* prim  = (const float*)d_in[1];
    float* out = (float*)d_out;

    GaussK gk;
    {
        double sigma = 13.0*0.15 + 0.35;   // 2.3
        double pdf[13], sum = 0.0;
        for (int i = 0; i < 13; ++i) {
            double t = (double)(i - 6);
            pdf[i] = exp(-0.5*(t/sigma)*(t/sigma));
            sum += pdf[i];
        }
        for (int i = 0; i < 13; ++i) gk.k[i] = (float)(pdf[i]/sum);
    }

    int nQuad = NB*HH*WW/4;               // 4,194,304
    k_hblur <<<nQuad/256,      256, 0, stream>>>(prim, out, gk);
    k_xscan <<<NB*HH/4,        256, 0, stream>>>(prim, out, gk);
    k_yscan <<<NB*8,          1024, 0, stream>>>(out, gk);
    k_sample<<<NB*HH*WW/2/256, 256, 0, stream>>>(image, out);
}

// Round 9
// 251.550 us; speedup vs baseline: 2.6294x; 1.0779x over previous
//
#include <hip/hip_runtime.h>
#include <math.h>

#define HH 512
#define WW 512
#define NB 64
#define HW (HH*WW)

struct GaussK { float k[13]; };

__device__ __forceinline__ float idenv(int i) {
    return (float)(2*i - (WW-1)) / (float)(WW-1);
}

#define DEF_OFF ((float)((2.0 + 4.0/511.0)/2.0))
#define BOUND   ((float)(2.0/512.0*8.0))

typedef float vf2 __attribute__((ext_vector_type(2), aligned(4)));

// horizontal 13-tap conv of one row held as a[8] per lane (cols 8l..8l+7),
// halo via neighbor-lane shuffles, reflect at row ends. Writes out[0..7].
__device__ __forceinline__ void hconv_row(const float (&a)[8], int lane, const GaussK& gk, float (&o)[8]) {
    float win[20];                       // cols 8l-6 .. 8l+13
    #pragma unroll
    for (int i = 0; i < 6; ++i) {
        float v = __shfl_up(a[i+2], 1, 64);
        win[i] = (lane == 0) ? a[6-i] : v;      // col i-6 < 0 -> reflect to 6-i
    }
    #pragma unroll
    for (int i = 6; i < 14; ++i) win[i] = a[i-6];
    #pragma unroll
    for (int i = 14; i < 20; ++i) {
        float v = __shfl_down(a[i-14], 1, 64);
        win[i] = (lane == 63) ? a[20-i] : v;    // col 512+k -> 510-k
    }
    #pragma unroll
    for (int j = 0; j < 8; ++j) {
        float acc = 0.f;
        #pragma unroll
        for (int i = 0; i < 13; ++i) acc = fmaf(gk.k[i], win[j+i], acc);
        o[j] = acc;
    }
}

// full x-channel pipeline for one row: hconv (9 wide incl col-1) + relu-diff scan
// + clips, store to plane0 row. a[8] = vblur'd values at cols 8l..8l+7.
__device__ __forceinline__ void xscan_row(const float (&a)[8], int lane, const GaussK& gk, float* row0) {
    float win[21];                       // cols 8l-7 .. 8l+13
    #pragma unroll
    for (int i = 0; i < 7; ++i) {
        float v = __shfl_up(a[i+1], 1, 64);
        win[i] = (lane == 0) ? a[7-i] : v;
    }
    #pragma unroll
    for (int i = 0; i < 8; ++i) win[7+i] = a[i];
    #pragma unroll
    for (int i = 15; i < 21; ++i) {
        float v = __shfl_down(a[i-15], 1, 64);
        win[i] = (lane == 63) ? a[21-i] : v;
    }
    float s[9];
    #pragma unroll
    for (int j = 0; j < 9; ++j) {
        float acc = 0.f;
        #pragma unroll
        for (int i = 0; i < 13; ++i) acc = fmaf(gk.k[i], win[j+i], acc);
        s[j] = acc + idenv(8*lane - 1 + j) + DEF_OFF;
    }
    if (lane == 0) s[0] = 0.f;

    float qs[8], q = 0.f;
    #pragma unroll
    for (int j = 1; j < 9; ++j) { q += fmaxf(s[j] - s[j-1], 0.f); qs[j-1] = q; }
    float inc = q;
    #pragma unroll
    for (int d = 1; d < 64; d <<= 1) {
        float t = __shfl_up(inc, d, 64);
        if (lane >= d) inc += t;
    }
    float excl = inc - q;

    float4 g0, g1;
    float* gp0 = (float*)&g0;
    float* gp1 = (float*)&g1;
    #pragma unroll
    for (int j = 0; j < 8; ++j) {
        int wcol = lane*8 + j;
        float sx = excl + qs[j];
        float p = sx - DEF_OFF - idenv(wcol);
        p = fminf(fmaxf(p, -BOUND), BOUND);
        float g = p + idenv(wcol);
        g = fminf(fmaxf(g, -1.f), 1.f);
        if (j < 4) gp0[j] = g; else gp1[j-4] = g;
    }
    *(float4*)(row0 + lane*8)     = g0;
    *(float4*)(row0 + lane*8 + 4) = g1;
}

// ---- fused prep: vblur(ch0)+hblur+row-scan -> plane0  AND  hblur(ch1) -> plane1 ----
// 256 thr = 4 waves; each wave owns TWO consecutive rows (h0, h0+1) of one batch:
// 14 shared vconv window rows for 2 outputs; hblur halo via shuffles (2 loads/row).
__global__ void __launch_bounds__(256) k_prep(const float* __restrict__ prim, float* __restrict__ out, GaussK gk) {
    int lane = threadIdx.x & 63;
    int bid  = (int)blockIdx.x;                  // 4096 blocks
    int work = (bid & 7)*512 + (bid >> 3);       // XCD-chunked, bijective
    int gw   = work*4 + ((int)threadIdx.x >> 6); // 0..16383
    int b    = gw >> 8;
    int h0   = (gw & 255)*2;

    const float4* src0 = (const float4*)(prim + (size_t)b*2*HW);       // ch0
    const float*  src1 = prim + ((size_t)b*2 + 1)*HW;                  // ch1
    float* plane0 = out + (size_t)b*3*HW;
    float* plane1 = out + ((size_t)b*3 + 1)*HW;

    // ---- ch0 vertical conv, rows h0 and h0+1, streaming 14-row window ----
    float a0[8] = {0,0,0,0,0,0,0,0};
    float a1[8] = {0,0,0,0,0,0,0,0};
    #pragma unroll
    for (int i = 0; i < 14; ++i) {
        int r = h0 - 6 + i;
        r = r < 0 ? -r : (r > HH-1 ? 2*(HH-1) - r : r);
        float4 u0 = src0[(size_t)r*128 + 2*lane];
        float4 u1 = src0[(size_t)r*128 + 2*lane + 1];
        float vv[8] = {u0.x,u0.y,u0.z,u0.w,u1.x,u1.y,u1.z,u1.w};
        if (i < 13) {
            #pragma unroll
            for (int j = 0; j < 8; ++j) a0[j] = fmaf(gk.k[i], vv[j], a0[j]);
        }
        if (i >= 1) {
            #pragma unroll
            for (int j = 0; j < 8; ++j) a1[j] = fmaf(gk.k[i-1], vv[j], a1[j]);
        }
    }

    // ---- hblur of ch1 rows h0, h0+1 -> plane1 ----
    #pragma unroll
    for (int r = 0; r < 2; ++r) {
        const float4* c4 = (const float4*)(src1 + (size_t)(h0+r)*WW);
        float4 u0 = c4[2*lane];
        float4 u1 = c4[2*lane + 1];
        float c[8] = {u0.x,u0.y,u0.z,u0.w,u1.x,u1.y,u1.z,u1.w};
        float o[8];
        hconv_row(c, lane, gk, o);
        float* row1 = plane1 + (size_t)(h0+r)*WW;
        *(float4*)(row1 + lane*8)     = make_float4(o[0],o[1],o[2],o[3]);
        *(float4*)(row1 + lane*8 + 4) = make_float4(o[4],o[5],o[6],o[7]);
    }

    // ---- x-channel scan rows h0, h0+1 -> plane0 ----
    xscan_row(a0, lane, gk, plane0 + (size_t)h0*WW);
    xscan_row(a1, lane, gk, plane0 + (size_t)(h0+1)*WW);
}

// ---- single-pass vertical blur + column scan: plane 1 -> plane 2 ----
__global__ void __launch_bounds__(1024) k_yscan(float* __restrict__ out, GaussK gk) {
    __shared__ float segsum[16][64];
    int b    = blockIdx.x >> 3;
    int wt   = blockIdx.x & 7;
    int lane = threadIdx.x & 63;
    int ws   = threadIdx.x >> 6;         // 0..15
    int w    = wt*64 + lane;
    const float* p1 = out + ((size_t)b*3 + 1)*HW + w;
    float*       p2 = out + ((size_t)b*3 + 2)*HW + w;
    int r0 = ws*32;

    float v[45];                          // rows r0-7 .. r0+37, reflected
    #pragma unroll
    for (int j = 0; j < 45; ++j) {
        int r = r0 - 7 + j;
        r = r < 0 ? -r : (r > HH-1 ? 2*(HH-1) - r : r);
        v[j] = p1[(size_t)r*WW];
    }

    float sprev;
    if (ws == 0) {
        sprev = 0.f;
    } else {
        float acc = 0.f;
        #pragma unroll
        for (int i = 0; i < 13; ++i) acc = fmaf(gk.k[i], v[i], acc);
        sprev = acc + idenv(r0 - 1) + DEF_OFF;
    }

    float q[32];
    float run = 0.f;
    #pragma unroll
    for (int n = 0; n < 32; ++n) {
        float acc = 0.f;
        #pragma unroll
        for (int i = 0; i < 13; ++i) acc = fmaf(gk.k[i], v[n+1+i], acc);
        float s = acc + idenv(r0 + n) + DEF_OFF;
        run += fmaxf(s - sprev, 0.f);
        q[n] = run;
        sprev = s;
    }
    segsum[ws][lane] = run;
    __syncthreads();
    float off = 0.f;
    for (int k = 0; k < ws; ++k) off += segsum[k][lane];

    #pragma unroll
    for (int n = 0; n < 32; ++n) {
        int h = r0 + n;
        float p = off + q[n] - DEF_OFF - idenv(h);
        p = fminf(fmaxf(p, -BOUND), BOUND);
        float g = p + idenv(h);
        g = fminf(fmaxf(g, -1.f), 1.f);
        p2[(size_t)h*WW] = g;
    }
}

// ---- bilinear grid sample: 1 px/lane, 2 batches/thread, float2 gathers, XCD swizzle ----
__global__ void __launch_bounds__(256) k_sample(const float* __restrict__ image, float* __restrict__ out) {
    int bid  = (int)blockIdx.x;                 // 32768 blocks
    int work = (bid & 7)*4096 + (bid >> 3);     // bijective, 32768%8==0
    int idx  = work*256 + threadIdx.x;          // over 32*H*W
    int w  = idx & (WW-1);
    int h  = (idx >> 9) & (HH-1);
    int b0 = idx >> 18;                         // 0..31
    int off = h*WW + w;

    #pragma unroll
    for (int u = 0; u < 2; ++u) {
        int b = b0 + 32*u;
        float* ob = out + (size_t)b*3*HW;
        const float* ib = image + (size_t)b*3*HW;
        float gx = ob[off];
        float gy = ob[2*HW + off];
        float fx = (gx + 1.f) * 0.5f * (float)(WW-1);
        float fy = (gy + 1.f) * 0.5f * (float)(HH-1);
        float x0f = floorf(fx), y0f = floorf(fy);
        float wx = fx - x0f, wy = fy - y0f;
        int x0 = (int)x0f, y0 = (int)y0f;
        int y1 = y0 + 1; if (y1 > HH-1) y1 = HH-1;
        bool sh = x0 > WW-2;                    // x0==511 => wx==0 exactly
        int xb = sh ? WW-2 : x0;
        size_t r0 = (size_t)y0*WW + xb;
        size_t r1 = (size_t)y1*WW + xb;
        float w11 = wx*wy;
        float w01 = wx - w11;
        float w10 = wy - w11;
        float w00 = 1.f - wx - wy + w11;
        #pragma unroll
        for (int c = 0; c < 3; ++c) {
            const float* ip = ib + (size_t)c*HW;
            vf2 t  = *(const vf2*)(ip + r0);
            vf2 bo = *(const vf2*)(ip + r1);
            float a00 = sh ? t.y  : t.x;
            float a10 = sh ? bo.y : bo.x;
            float r = a00*w00 + t.y*w01 + a10*w10 + bo.y*w11;
            __builtin_nontemporal_store(r, ob + (size_t)c*HW + off);
        }
    }
}

extern "C" void kernel_launch(void* const* d_in, const int* in_sizes, int n_in,
                              void* d_out, int out_size, void* d_ws, size_t ws_size,
                              hipStream_t stream) {
    const float* image = (const float*)d_in[0];
    const float* prim  = (const float*)d_in[1];
    float* out = (float*)d_out;

    GaussK gk;
    {
        double sigma = 13.0*0.15 + 0.35;   // 2.3
        double pdf[13], sum = 0.0;
        for (int i = 0; i < 13; ++i) {
            double t = (double)(i - 6);
            pdf[i] = exp(-0.5*(t/sigma)*(t/sigma));
            sum += pdf[i];
        }
        for (int i = 0; i < 13; ++i) gk.k[i] = (float)(pdf[i]/sum);
    }

    k_prep  <<<4096,           256, 0, stream>>>(prim, out, gk);
    k_yscan <<<NB*8,          1024, 0, stream>>>(out, gk);
    k_sample<<<NB*HH*WW/2/256, 256, 0, stream>>>(image, out);
}

// Round 10
// 244.810 us; speedup vs baseline: 2.7018x; 1.0275x over previous
//
#include <hip/hip_runtime.h>
#include <math.h>

#define HH 512
#define WW 512
#define NB 64
#define HW (HH*WW)

struct GaussK { float k[13]; };

__device__ __forceinline__ float idenv(int i) {
    return (float)(2*i - (WW-1)) / (float)(WW-1);
}

#define DEF_OFF ((float)((2.0 + 4.0/511.0)/2.0))
#define BOUND   ((float)(2.0/512.0*8.0))

typedef float vf2 __attribute__((ext_vector_type(2), aligned(4)));

// horizontal 13-tap conv of one row held as a[8] per lane (cols 8l..8l+7),
// halo via neighbor-lane shuffles, reflect at row ends.
__device__ __forceinline__ void hconv_row(const float (&a)[8], int lane, const GaussK& gk, float (&o)[8]) {
    float win[20];                       // cols 8l-6 .. 8l+13
    #pragma unroll
    for (int i = 0; i < 6; ++i) {
        float v = __shfl_up(a[i+2], 1, 64);
        win[i] = (lane == 0) ? a[6-i] : v;
    }
    #pragma unroll
    for (int i = 6; i < 14; ++i) win[i] = a[i-6];
    #pragma unroll
    for (int i = 14; i < 20; ++i) {
        float v = __shfl_down(a[i-14], 1, 64);
        win[i] = (lane == 63) ? a[20-i] : v;
    }
    #pragma unroll
    for (int j = 0; j < 8; ++j) {
        float acc = 0.f;
        #pragma unroll
        for (int i = 0; i < 13; ++i) acc = fmaf(gk.k[i], win[j+i], acc);
        o[j] = acc;
    }
}

// x-channel pipeline for one row: hconv (incl col-1) + relu-diff scan + clips.
__device__ __forceinline__ void xscan_row(const float (&a)[8], int lane, const GaussK& gk, float* row0) {
    float win[21];                       // cols 8l-7 .. 8l+13
    #pragma unroll
    for (int i = 0; i < 7; ++i) {
        float v = __shfl_up(a[i+1], 1, 64);
        win[i] = (lane == 0) ? a[7-i] : v;
    }
    #pragma unroll
    for (int i = 0; i < 8; ++i) win[7+i] = a[i];
    #pragma unroll
    for (int i = 15; i < 21; ++i) {
        float v = __shfl_down(a[i-15], 1, 64);
        win[i] = (lane == 63) ? a[21-i] : v;
    }
    float s[9];
    #pragma unroll
    for (int j = 0; j < 9; ++j) {
        float acc = 0.f;
        #pragma unroll
        for (int i = 0; i < 13; ++i) acc = fmaf(gk.k[i], win[j+i], acc);
        s[j] = acc + idenv(8*lane - 1 + j) + DEF_OFF;
    }
    if (lane == 0) s[0] = 0.f;

    float qs[8], q = 0.f;
    #pragma unroll
    for (int j = 1; j < 9; ++j) { q += fmaxf(s[j] - s[j-1], 0.f); qs[j-1] = q; }
    float inc = q;
    #pragma unroll
    for (int d = 1; d < 64; d <<= 1) {
        float t = __shfl_up(inc, d, 64);
        if (lane >= d) inc += t;
    }
    float excl = inc - q;

    float4 g0, g1;
    float* gp0 = (float*)&g0;
    float* gp1 = (float*)&g1;
    #pragma unroll
    for (int j = 0; j < 8; ++j) {
        int wcol = lane*8 + j;
        float sx = excl + qs[j];
        float p = sx - DEF_OFF - idenv(wcol);
        p = fminf(fmaxf(p, -BOUND), BOUND);
        float g = p + idenv(wcol);
        g = fminf(fmaxf(g, -1.f), 1.f);
        if (j < 4) gp0[j] = g; else gp1[j-4] = g;
    }
    *(float4*)(row0 + lane*8)     = g0;
    *(float4*)(row0 + lane*8 + 4) = g1;
}

// ---- fused prep: vblur(ch0)+hblur+row-scan -> plane0  AND  hblur(ch1) -> plane1 ----
__global__ void __launch_bounds__(256) k_prep(const float* __restrict__ prim, float* __restrict__ out, GaussK gk) {
    int lane = threadIdx.x & 63;
    int bid  = (int)blockIdx.x;                  // 4096 blocks
    int work = (bid & 7)*512 + (bid >> 3);       // XCD-chunked, bijective
    int gw   = work*4 + ((int)threadIdx.x >> 6); // 0..16383
    int b    = gw >> 8;
    int h0   = (gw & 255)*2;

    const float4* src0 = (const float4*)(prim + (size_t)b*2*HW);       // ch0
    const float*  src1 = prim + ((size_t)b*2 + 1)*HW;                  // ch1
    float* plane0 = out + (size_t)b*3*HW;
    float* plane1 = out + ((size_t)b*3 + 1)*HW;

    float a0[8] = {0,0,0,0,0,0,0,0};
    float a1[8] = {0,0,0,0,0,0,0,0};
    #pragma unroll
    for (int i = 0; i < 14; ++i) {
        int r = h0 - 6 + i;
        r = r < 0 ? -r : (r > HH-1 ? 2*(HH-1) - r : r);
        float4 u0 = src0[(size_t)r*128 + 2*lane];
        float4 u1 = src0[(size_t)r*128 + 2*lane + 1];
        float vv[8] = {u0.x,u0.y,u0.z,u0.w,u1.x,u1.y,u1.z,u1.w};
        if (i < 13) {
            #pragma unroll
            for (int j = 0; j < 8; ++j) a0[j] = fmaf(gk.k[i], vv[j], a0[j]);
        }
        if (i >= 1) {
            #pragma unroll
            for (int j = 0; j < 8; ++j) a1[j] = fmaf(gk.k[i-1], vv[j], a1[j]);
        }
    }

    #pragma unroll
    for (int r = 0; r < 2; ++r) {
        const float4* c4 = (const float4*)(src1 + (size_t)(h0+r)*WW);
        float4 u0 = c4[2*lane];
        float4 u1 = c4[2*lane + 1];
        float c[8] = {u0.x,u0.y,u0.z,u0.w,u1.x,u1.y,u1.z,u1.w};
        float o[8];
        hconv_row(c, lane, gk, o);
        float* row1 = plane1 + (size_t)(h0+r)*WW;
        *(float4*)(row1 + lane*8)     = make_float4(o[0],o[1],o[2],o[3]);
        *(float4*)(row1 + lane*8 + 4) = make_float4(o[4],o[5],o[6],o[7]);
    }

    xscan_row(a0, lane, gk, plane0 + (size_t)h0*WW);
    xscan_row(a1, lane, gk, plane0 + (size_t)(h0+1)*WW);
}

// ---- fused y-scan + bilinear sample: plane1 -> grid-y (regs) -> final output ----
// 1024 thr = 16 waves; wave ws owns rows [ws*32,+32) for 64 consecutive columns.
// All plane1 reads happen BEFORE the barrier; all out writes after it.
// plane0 (grid-x) elements are read-then-overwritten by the same thread.
__global__ void __launch_bounds__(1024) k_yssamp(const float* __restrict__ image, float* __restrict__ out, GaussK gk) {
    __shared__ float segsum[16][64];
    int b    = blockIdx.x >> 3;
    int wt   = blockIdx.x & 7;
    int lane = threadIdx.x & 63;
    int ws   = threadIdx.x >> 6;         // 0..15
    int w    = wt*64 + lane;
    const float* p1 = out + ((size_t)b*3 + 1)*HW + w;
    int r0 = ws*32;

    float v[45];                          // plane1 rows r0-7 .. r0+37, reflected
    #pragma unroll
    for (int j = 0; j < 45; ++j) {
        int r = r0 - 7 + j;
        r = r < 0 ? -r : (r > HH-1 ? 2*(HH-1) - r : r);
        v[j] = p1[(size_t)r*WW];
    }

    float sprev;
    if (ws == 0) {
        sprev = 0.f;
    } else {
        float acc = 0.f;
        #pragma unroll
        for (int i = 0; i < 13; ++i) acc = fmaf(gk.k[i], v[i], acc);
        sprev = acc + idenv(r0 - 1) + DEF_OFF;
    }

    float q[32];
    float run = 0.f;
    #pragma unroll
    for (int n = 0; n < 32; ++n) {
        float acc = 0.f;
        #pragma unroll
        for (int i = 0; i < 13; ++i) acc = fmaf(gk.k[i], v[n+1+i], acc);
        float s = acc + idenv(r0 + n) + DEF_OFF;
        run += fmaxf(s - sprev, 0.f);
        q[n] = run;
        sprev = s;
    }
    segsum[ws][lane] = run;
    __syncthreads();
    float off = 0.f;
    for (int k = 0; k < ws; ++k) off += segsum[k][lane];

    const float* ib = image + (size_t)b*3*HW;
    float*       ob = out   + (size_t)b*3*HW;

    #pragma unroll
    for (int n = 0; n < 32; ++n) {
        int h = r0 + n;
        size_t poff = (size_t)h*WW + w;
        // grid-y from registers
        float p = off + q[n] - DEF_OFF - idenv(h);
        p = fminf(fmaxf(p, -BOUND), BOUND);
        float gy = p + idenv(h);
        gy = fminf(fmaxf(gy, -1.f), 1.f);
        // grid-x from plane0 (coalesced; same element overwritten below)
        float gx = ob[poff];

        float fx = (gx + 1.f) * 0.5f * (float)(WW-1);
        float fy = (gy + 1.f) * 0.5f * (float)(HH-1);
        float x0f = floorf(fx), y0f = floorf(fy);
        float wx = fx - x0f, wy = fy - y0f;
        int x0 = (int)x0f, y0 = (int)y0f;
        int y1 = y0 + 1; if (y1 > HH-1) y1 = HH-1;
        bool shx = x0 > WW-2;               // x0==511 => wx==0 exactly
        int xb = shx ? WW-2 : x0;
        size_t g0 = (size_t)y0*WW + xb;
        size_t g1 = (size_t)y1*WW + xb;
        float w11 = wx*wy;
        float w01 = wx - w11;
        float w10 = wy - w11;
        float w00 = 1.f - wx - wy + w11;
        #pragma unroll
        for (int c = 0; c < 3; ++c) {
            const float* ip = ib + (size_t)c*HW;
            vf2 t  = *(const vf2*)(ip + g0);
            vf2 bo = *(const vf2*)(ip + g1);
            float a00 = shx ? t.y  : t.x;
            float a10 = shx ? bo.y : bo.x;
            float r = a00*w00 + t.y*w01 + a10*w10 + bo.y*w11;
            __builtin_nontemporal_store(r, ob + (size_t)c*HW + poff);
        }
    }
}

extern "C" void kernel_launch(void* const* d_in, const int* in_sizes, int n_in,
                              void* d_out, int out_size, void* d_ws, size_t ws_size,
                              hipStream_t stream) {
    const float* image = (const float*)d_in[0];
    const float* prim  = (const float*)d_in[1];
    float* out = (float*)d_out;

    GaussK gk;
    {
        double sigma = 13.0*0.15 + 0.35;   // 2.3
        double pdf[13], sum = 0.0;
        for (int i = 0; i < 13; ++i) {
            double t = (double)(i - 6);
            pdf[i] = exp(-0.5*(t/sigma)*(t/sigma));
            sum += pdf[i];
        }
        for (int i = 0; i < 13; ++i) gk.k[i] = (float)(pdf[i]/sum);
    }

    k_prep  <<<4096, 256,  0, stream>>>(prim, out, gk);
    k_yssamp<<<NB*8, 1024, 0, stream>>>(image, out, gk);
}

// Round 11
// 229.865 us; speedup vs baseline: 2.8775x; 1.0650x over previous
//
#include <hip/hip_runtime.h>
#include <math.h>

#define HH 512
#define WW 512
#define NB 64
#define HW (HH*WW)

struct GaussK { float k[13]; };

__device__ __forceinline__ float idenv(int i) {
    return (float)(2*i - (WW-1)) / (float)(WW-1);
}

#define DEF_OFF ((float)((2.0 + 4.0/511.0)/2.0))
#define BOUND   ((float)(2.0/512.0*8.0))

typedef float vf2 __attribute__((ext_vector_type(2), aligned(4)));

// horizontal 13-tap conv of one row held as a[8] per lane (cols 8l..8l+7),
// halo via neighbor-lane shuffles, reflect at row ends.
__device__ __forceinline__ void hconv_row(const float (&a)[8], int lane, const GaussK& gk, float (&o)[8]) {
    float win[20];                       // cols 8l-6 .. 8l+13
    #pragma unroll
    for (int i = 0; i < 6; ++i) {
        float v = __shfl_up(a[i+2], 1, 64);
        win[i] = (lane == 0) ? a[6-i] : v;
    }
    #pragma unroll
    for (int i = 6; i < 14; ++i) win[i] = a[i-6];
    #pragma unroll
    for (int i = 14; i < 20; ++i) {
        float v = __shfl_down(a[i-14], 1, 64);
        win[i] = (lane == 63) ? a[20-i] : v;
    }
    #pragma unroll
    for (int j = 0; j < 8; ++j) {
        float acc = 0.f;
        #pragma unroll
        for (int i = 0; i < 13; ++i) acc = fmaf(gk.k[i], win[j+i], acc);
        o[j] = acc;
    }
}

// x-channel pipeline for one row: hconv (incl col-1) + relu-diff scan + clips.
__device__ __forceinline__ void xscan_row(const float (&a)[8], int lane, const GaussK& gk, float* row0) {
    float win[21];                       // cols 8l-7 .. 8l+13
    #pragma unroll
    for (int i = 0; i < 7; ++i) {
        float v = __shfl_up(a[i+1], 1, 64);
        win[i] = (lane == 0) ? a[7-i] : v;
    }
    #pragma unroll
    for (int i = 0; i < 8; ++i) win[7+i] = a[i];
    #pragma unroll
    for (int i = 15; i < 21; ++i) {
        float v = __shfl_down(a[i-15], 1, 64);
        win[i] = (lane == 63) ? a[21-i] : v;
    }
    float s[9];
    #pragma unroll
    for (int j = 0; j < 9; ++j) {
        float acc = 0.f;
        #pragma unroll
        for (int i = 0; i < 13; ++i) acc = fmaf(gk.k[i], win[j+i], acc);
        s[j] = acc + idenv(8*lane - 1 + j) + DEF_OFF;
    }
    if (lane == 0) s[0] = 0.f;

    float qs[8], q = 0.f;
    #pragma unroll
    for (int j = 1; j < 9; ++j) { q += fmaxf(s[j] - s[j-1], 0.f); qs[j-1] = q; }
    float inc = q;
    #pragma unroll
    for (int d = 1; d < 64; d <<= 1) {
        float t = __shfl_up(inc, d, 64);
        if (lane >= d) inc += t;
    }
    float excl = inc - q;

    float4 g0, g1;
    float* gp0 = (float*)&g0;
    float* gp1 = (float*)&g1;
    #pragma unroll
    for (int j = 0; j < 8; ++j) {
        int wcol = lane*8 + j;
        float sx = excl + qs[j];
        float p = sx - DEF_OFF - idenv(wcol);
        p = fminf(fmaxf(p, -BOUND), BOUND);
        float g = p + idenv(wcol);
        g = fminf(fmaxf(g, -1.f), 1.f);
        if (j < 4) gp0[j] = g; else gp1[j-4] = g;
    }
    *(float4*)(row0 + lane*8)     = g0;
    *(float4*)(row0 + lane*8 + 4) = g1;
}

// ---- fused prep: vblur(ch0)+hblur+row-scan -> plane0  AND  hblur(ch1) -> plane1 ----
__global__ void __launch_bounds__(256) k_prep(const float* __restrict__ prim, float* __restrict__ out, GaussK gk) {
    int lane = threadIdx.x & 63;
    int bid  = (int)blockIdx.x;                  // 4096 blocks
    int work = (bid & 7)*512 + (bid >> 3);       // XCD-chunked, bijective
    int gw   = work*4 + ((int)threadIdx.x >> 6); // 0..16383
    int b    = gw >> 8;
    int h0   = (gw & 255)*2;

    const float4* src0 = (const float4*)(prim + (size_t)b*2*HW);       // ch0
    const float*  src1 = prim + ((size_t)b*2 + 1)*HW;                  // ch1
    float* plane0 = out + (size_t)b*3*HW;
    float* plane1 = out + ((size_t)b*3 + 1)*HW;

    float a0[8] = {0,0,0,0,0,0,0,0};
    float a1[8] = {0,0,0,0,0,0,0,0};
    #pragma unroll
    for (int i = 0; i < 14; ++i) {
        int r = h0 - 6 + i;
        r = r < 0 ? -r : (r > HH-1 ? 2*(HH-1) - r : r);
        float4 u0 = src0[(size_t)r*128 + 2*lane];
        float4 u1 = src0[(size_t)r*128 + 2*lane + 1];
        float vv[8] = {u0.x,u0.y,u0.z,u0.w,u1.x,u1.y,u1.z,u1.w};
        if (i < 13) {
            #pragma unroll
            for (int j = 0; j < 8; ++j) a0[j] = fmaf(gk.k[i], vv[j], a0[j]);
        }
        if (i >= 1) {
            #pragma unroll
            for (int j = 0; j < 8; ++j) a1[j] = fmaf(gk.k[i-1], vv[j], a1[j]);
        }
    }

    #pragma unroll
    for (int r = 0; r < 2; ++r) {
        const float4* c4 = (const float4*)(src1 + (size_t)(h0+r)*WW);
        float4 u0 = c4[2*lane];
        float4 u1 = c4[2*lane + 1];
        float c[8] = {u0.x,u0.y,u0.z,u0.w,u1.x,u1.y,u1.z,u1.w};
        float o[8];
        hconv_row(c, lane, gk, o);
        float* row1 = plane1 + (size_t)(h0+r)*WW;
        *(float4*)(row1 + lane*8)     = make_float4(o[0],o[1],o[2],o[3]);
        *(float4*)(row1 + lane*8 + 4) = make_float4(o[4],o[5],o[6],o[7]);
    }

    xscan_row(a0, lane, gk, plane0 + (size_t)h0*WW);
    xscan_row(a1, lane, gk, plane0 + (size_t)(h0+1)*WW);
}

// ---- fused y-scan + bilinear sample: plane1 -> grid-y (regs) -> final output ----
// 1024 thr = 16 waves; wave ws owns rows [ws*32,+32) for 64 consecutive columns.
// launch_bounds(1024,4): allow up to 128 VGPR for deep gather pipelining.
// XCD-chunked: each XCD owns 8 consecutive batches -> image gathers L2-resident.
__global__ void __launch_bounds__(1024, 4) k_yssamp(const float* __restrict__ image, float* __restrict__ out, GaussK gk) {
    __shared__ float segsum[16][64];
    int bid  = (int)blockIdx.x;          // 512 blocks
    int work = (bid & 7)*64 + (bid >> 3);// XCD j -> works [j*64,(j+1)*64) = batches j*8..j*8+7
    int b    = work >> 3;
    int wt   = work & 7;
    int lane = threadIdx.x & 63;
    int ws   = threadIdx.x >> 6;         // 0..15
    int w    = wt*64 + lane;
    const float* p1 = out + ((size_t)b*3 + 1)*HW + w;
    int r0 = ws*32;

    float v[45];                          // plane1 rows r0-7 .. r0+37, reflected
    #pragma unroll
    for (int j = 0; j < 45; ++j) {
        int r = r0 - 7 + j;
        r = r < 0 ? -r : (r > HH-1 ? 2*(HH-1) - r : r);
        v[j] = p1[(size_t)r*WW];
    }

    float sprev;
    if (ws == 0) {
        sprev = 0.f;
    } else {
        float acc = 0.f;
        #pragma unroll
        for (int i = 0; i < 13; ++i) acc = fmaf(gk.k[i], v[i], acc);
        sprev = acc + idenv(r0 - 1) + DEF_OFF;
    }

    float q[32];
    float run = 0.f;
    #pragma unroll
    for (int n = 0; n < 32; ++n) {
        float acc = 0.f;
        #pragma unroll
        for (int i = 0; i < 13; ++i) acc = fmaf(gk.k[i], v[n+1+i], acc);
        float s = acc + idenv(r0 + n) + DEF_OFF;
        run += fmaxf(s - sprev, 0.f);
        q[n] = run;
        sprev = s;
    }
    segsum[ws][lane] = run;
    __syncthreads();
    float off = 0.f;
    for (int k = 0; k < ws; ++k) off += segsum[k][lane];

    const float* ib = image + (size_t)b*3*HW;
    float*       ob = out   + (size_t)b*3*HW;

    // batch-load all 32 grid-x values (coalesced, v[] is dead -> VGPR available)
    float gxv[32];
    #pragma unroll
    for (int n = 0; n < 32; ++n)
        gxv[n] = ob[(size_t)(r0 + n)*WW + w];

    #pragma unroll
    for (int n = 0; n < 32; ++n) {
        int h = r0 + n;
        size_t poff = (size_t)h*WW + w;
        float p = off + q[n] - DEF_OFF - idenv(h);
        p = fminf(fmaxf(p, -BOUND), BOUND);
        float gy = p + idenv(h);
        gy = fminf(fmaxf(gy, -1.f), 1.f);
        float gx = gxv[n];

        float fx = (gx + 1.f) * 0.5f * (float)(WW-1);
        float fy = (gy + 1.f) * 0.5f * (float)(HH-1);
        float x0f = floorf(fx), y0f = floorf(fy);
        float wx = fx - x0f, wy = fy - y0f;
        int x0 = (int)x0f, y0 = (int)y0f;
        int y1 = y0 + 1; if (y1 > HH-1) y1 = HH-1;
        bool shx = x0 > WW-2;               // x0==511 => wx==0 exactly
        int xb = shx ? WW-2 : x0;
        size_t g0 = (size_t)y0*WW + xb;
        size_t g1 = (size_t)y1*WW + xb;
        float w11 = wx*wy;
        float w01 = wx - w11;
        float w10 = wy - w11;
        float w00 = 1.f - wx - wy + w11;
        #pragma unroll
        for (int c = 0; c < 3; ++c) {
            const float* ip = ib + (size_t)c*HW;
            vf2 t  = *(const vf2*)(ip + g0);
            vf2 bo = *(const vf2*)(ip + g1);
            float a00 = shx ? t.y  : t.x;
            float a10 = shx ? bo.y : bo.x;
            float r = a00*w00 + t.y*w01 + a10*w10 + bo.y*w11;
            __builtin_nontemporal_store(r, ob + (size_t)c*HW + poff);
        }
    }
}

extern "C" void kernel_launch(void* const* d_in, const int* in_sizes, int n_in,
                              void* d_out, int out_size, void* d_ws, size_t ws_size,
                              hipStream_t stream) {
    const float* image = (const float*)d_in[0];
    const float* prim  = (const float*)d_in[1];
    float* out = (float*)d_out;

    GaussK gk;
    {
        double sigma = 13.0*0.15 + 0.35;   // 2.3
        double pdf[13], sum = 0.0;
        for (int i = 0; i < 13; ++i) {
            double t = (double)(i - 6);
            pdf[i] = exp(-0.5*(t/sigma)*(t/sigma));
            sum += pdf[i];
        }
        for (int i = 0; i < 13; ++i) gk.k[i] = (float)(pdf[i]/sum);
    }

    k_prep  <<<4096, 256,  0, stream>>>(prim, out, gk);
    k_yssamp<<<NB*8, 1024, 0, stream>>>(image, out, gk);
}